// Round 18
// baseline (81.685 us; speedup 1.0000x reference)
//
#include <hip/hip_runtime.h>
#include <stdint.h>

// Problem dims (fixed by reference)
#define BB 8
#define LL 4096
#define DD 1024
#define MM 2048
#define CC 16            // chunk length for the two-level scan
#define NC (MM / CC)     // 128 chunks

// ---- workspace layout (bytes) ----
#define OFF_CIDX   0                                   // B*L i32    = 131072
#define OFF_DECAY  (OFF_CIDX   + (size_t)BB*LL*4)      // B*M  f32   = 65536
#define OFF_PPRE   (OFF_DECAY  + (size_t)BB*MM*4)      // B*M  f32   = 65536
#define OFF_A      (OFF_PPRE   + (size_t)BB*MM*4)      // B*NC f32   = 4096
#define OFF_HSTART (OFF_A      + (size_t)BB*NC*4)      // B*NC*D bf16 = 2 MB
#define OFF_HLOC   (OFF_HSTART + (size_t)BB*NC*DD*2)   // B*M*D bf16 = 32 MB
#define WS_NEEDED  (OFF_HLOC   + (size_t)BB*MM*DD*2)

// native clang vector types (accepted by __builtin_nontemporal_*)
typedef float          f32x4 __attribute__((ext_vector_type(4)));
typedef unsigned short u16x4 __attribute__((ext_vector_type(4)));

// ---- bf16 helpers (RNE, hand-rolled: exact bit semantics) ------------------
__device__ __forceinline__ unsigned short f2bf(float f) {
    union { float f; uint32_t u; } v; v.f = f;
    uint32_t r = v.u + 0x7FFFu + ((v.u >> 16) & 1u);
    return (unsigned short)(r >> 16);
}
__device__ __forceinline__ float bf2f(unsigned short h) {
    union { uint32_t u; float f; } v; v.u = ((uint32_t)h) << 16;
    return v.f;
}

// ============================================================================
// K1: per-batch mask cumsum, decay scatter, within-chunk prefix products.
// One block per batch; 1024 threads = 16 waves; shuffle-based scan.
// [round-14 verbatim]
// ============================================================================
__global__ __launch_bounds__(1024) void k_prep(
    const void* __restrict__ mask_raw,
    const float* __restrict__ prob,
    int* __restrict__ chunk_idx,      // (B,L)
    float* __restrict__ decay,        // (B,M)
    float* __restrict__ ppre,         // (B,M)
    float* __restrict__ abuf)         // (B,NC)
{
    const int b    = blockIdx.x;
    const int tid  = threadIdx.x;
    const int lane = tid & 63;
    const int wid  = tid >> 6;        // 0..15

    __shared__ int s_f32, s_bool;
    __shared__ int s_wsum[16];
    __shared__ int s_woff[17];
    __shared__ float s_decay[MM];

    // ---- detect mask storage: scan first 32768 bytes (safe in all layouts) --
    const uint32_t* w = (const uint32_t*)mask_raw;
    int lf32 = 0, lbool = 0;
    for (int i = tid; i < 8192; i += 1024) {
        uint32_t v = w[i];
        if (v == 0x3F800000u) lf32 = 1;          // a 1.0f word -> f32 storage
        if (v & 0xFFFFFF00u)  lbool = 1;         // nonzero high bytes -> 1-byte
    }
    if (tid == 0) { s_f32 = 0; s_bool = 0; s_woff[0] = 0; }
    for (int j = tid; j < MM; j += 1024) s_decay[j] = 1.0f;
    __syncthreads();
    if (lf32)  s_f32 = 1;
    if (lbool) s_bool = 1;
    __syncthreads();
    const int mode = s_f32 ? 2 : (s_bool ? 1 : 0);   // 2=f32, 1=byte, 0=int32

    auto rdmask = [&](int l) -> int {
        size_t idx = (size_t)b * LL + l;
        if (mode == 2) return ((const float*)mask_raw)[idx] != 0.0f;
        if (mode == 1) return ((const unsigned char*)mask_raw)[idx] != 0;
        return ((const int*)mask_raw)[idx] != 0;
    };

    const int l0 = tid * 4;
    const int m0 = rdmask(l0 + 0);
    const int m1 = rdmask(l0 + 1);
    const int m2 = rdmask(l0 + 2);
    const int m3 = rdmask(l0 + 3);
    const int s  = m0 + m1 + m2 + m3;

    // wave-level inclusive scan of per-thread sums (no barriers)
    int incl = s;
    #pragma unroll
    for (int off = 1; off < 64; off <<= 1) {
        int v = __shfl_up(incl, off);
        if (lane >= off) incl += v;
    }
    if (lane == 63) s_wsum[wid] = incl;
    __syncthreads();

    // wave 0 scans the 16 wave totals
    if (wid == 0) {
        int v = (lane < 16) ? s_wsum[lane] : 0;
        #pragma unroll
        for (int off = 1; off < 16; off <<= 1) {
            int u = __shfl_up(v, off);
            if (lane >= off) v += u;
        }
        if (lane < 16) s_woff[lane + 1] = v;
    }
    __syncthreads();

    const int excl = s_woff[wid] + incl - s;   // tokens before this thread's 4

    const int c0 = excl + m0;
    const int c1 = c0 + m1;
    const int c2 = c1 + m2;
    const int c3 = c2 + m3;

    chunk_idx[(size_t)b * LL + l0 + 0] = c0 - 1;
    chunk_idx[(size_t)b * LL + l0 + 1] = c1 - 1;
    chunk_idx[(size_t)b * LL + l0 + 2] = c2 - 1;
    chunk_idx[(size_t)b * LL + l0 + 3] = c3 - 1;

    // scatter decay = clamp(1-prob,0,1) at masked slots (into LDS)
    if (m0) { float v = 1.0f - prob[(size_t)b*LL + l0+0]; s_decay[c0-1] = fminf(fmaxf(v,0.f),1.f); }
    if (m1) { float v = 1.0f - prob[(size_t)b*LL + l0+1]; s_decay[c1-1] = fminf(fmaxf(v,0.f),1.f); }
    if (m2) { float v = 1.0f - prob[(size_t)b*LL + l0+2]; s_decay[c2-1] = fminf(fmaxf(v,0.f),1.f); }
    if (m3) { float v = 1.0f - prob[(size_t)b*LL + l0+3]; s_decay[c3-1] = fminf(fmaxf(v,0.f),1.f); }
    __syncthreads();

    for (int j = tid; j < MM; j += 1024) decay[(size_t)b * MM + j] = s_decay[j];
    if (tid < NC) {
        float p = 1.0f;
        const int t0 = tid * CC;
        #pragma unroll
        for (int t = 0; t < CC; ++t) {
            p *= s_decay[t0 + t];
            ppre[(size_t)b * MM + t0 + t] = p;
        }
        abuf[b * NC + tid] = p;
    }
}

// ============================================================================
// K2: per-chunk local EMA scans (zero init), bf16 output. Plain cached loads.
// grid = (NC, B), 256 threads. [round-14 verbatim]
// ============================================================================
__global__ __launch_bounds__(256) void k_localscan(
    const float* __restrict__ hid,     // (B,M,D) f32
    const float* __restrict__ decay,   // (B,M)
    const int* __restrict__ counts,
    unsigned short* __restrict__ hloc) // (B,M,D) bf16
{
    const int c = blockIdx.x;
    const int b = blockIdx.y;
    const int count = counts[b];
    const int tstart = c * CC;
    const int tend = min(CC, count - tstart);
    if (tend <= 0) return;

    __shared__ float s_a[CC];
    if (threadIdx.x < CC) s_a[threadIdx.x] = decay[(size_t)b * MM + tstart + threadIdx.x];
    __syncthreads();

    const int d4 = threadIdx.x;
    const float4*  x = (const float4*)(hid + ((size_t)b * MM + tstart) * DD) + d4;
    ushort4*       o = (ushort4*)(hloc + ((size_t)b * MM + tstart) * DD) + d4;

    float4 h = make_float4(0.f, 0.f, 0.f, 0.f);
    #pragma unroll 4
    for (int t = 0; t < tend; ++t) {
        const float a  = s_a[t];
        const float om = 1.0f - a;
        const float4 xv = x[(size_t)t * (DD / 4)];
        h.x = fmaf(a, h.x, om * xv.x);
        h.y = fmaf(a, h.y, om * xv.y);
        h.z = fmaf(a, h.z, om * xv.z);
        h.w = fmaf(a, h.w, om * xv.w);
        ushort4 u;
        u.x = f2bf(h.x); u.y = f2bf(h.y); u.z = f2bf(h.z); u.w = f2bf(h.w);
        o[(size_t)t * (DD / 4)] = u;
    }
}

// ============================================================================
// K3: parallel (Kogge-Stone) scan over the 128 chunks -> chunk-start states
// (bf16) and new_state (f32). grid = (D/2, B). [round-14 verbatim]
// ============================================================================
__global__ __launch_bounds__(256) void k_scan(
    const float* __restrict__ state,            // (B,D)
    const float* __restrict__ abuf,             // (B,NC)
    const unsigned short* __restrict__ hloc,    // (B,M,D) bf16
    const int* __restrict__ counts,
    unsigned short* __restrict__ hstart,        // (B,NC,D) bf16
    float* __restrict__ out_state)              // (B,D) f32
{
    const int g  = blockIdx.x;             // channel group of 2
    const int b  = blockIdx.y;
    const int tid = threadIdx.x;
    const int c  = tid >> 1;               // 0..127
    const int i  = tid & 1;
    const int ch = g * 2 + i;
    const int count = counts[b];
    const int tstart = c * CC;

    float a = abuf[b * NC + c];
    float e = 0.0f;
    if (tstart < count) {
        const int row = min(tstart + CC - 1, count - 1);
        e = bf2f(hloc[((size_t)b * MM + row) * DD + ch]);
    }

    __shared__ float s_a[NC];
    __shared__ float s_e[NC][2];

    for (int off = 1; off < NC; off <<= 1) {
        s_a[c] = a;              // 2 threads write the same value: benign
        s_e[c][i] = e;
        __syncthreads();
        if (c >= off) {
            const float ap = s_a[c - off];
            const float ep = s_e[c - off][i];
            e = fmaf(a, ep, e);
            a = a * ap;
        }
        __syncthreads();
    }
    s_a[c] = a;
    s_e[c][i] = e;
    __syncthreads();

    const float st = state[(size_t)b * DD + ch];
    const float hs = (c == 0) ? st : fmaf(s_a[c - 1], st, s_e[c - 1][i]);
    hstart[((size_t)b * NC + c) * DD + ch] = f2bf(hs);
    if (c == NC - 1) out_state[(size_t)b * DD + ch] = fmaf(a, st, e);
}

// ============================================================================
// K4: output = residual + gathered EMA; 4 consecutive rows per block (ILP +
// j-sharing: adjacent rows share the gathered hloc/hstart row ~2.3x on avg);
// XCD-chunked swizzle: swz=(bid&7)*1024+(bid>>3), bijective on 8192 blocks,
// one contiguous batch per XCD. NT stores on out. grid = B*L/4 = 8192.
// ============================================================================
__global__ __launch_bounds__(256) void k_output(
    const float* __restrict__ residual,         // (B,L,D)
    const int* __restrict__ chunk_idx,          // (B,L)
    const float* __restrict__ ppre,             // (B,M)
    const unsigned short* __restrict__ hstart,  // (B,NC,D) bf16
    const unsigned short* __restrict__ hloc,    // (B,M,D) bf16
    float* __restrict__ out)                    // (B,L,D)
{
    // XCD-chunked bijective swizzle (8192 = 8 * 1024)
    const int swz = ((blockIdx.x & 7) << 10) | (blockIdx.x >> 3);
    const int bl0 = swz * 4;            // first of 4 rows (same batch: 4096%4==0)
    const int b   = bl0 >> 12;          // L = 4096
    const int d4  = threadIdx.x;

    // 4 row indices (int4 load: cidx is 16B aligned at bl0*4 bytes)
    const int4 jv = *(const int4*)(chunk_idx + bl0);
    const int j[4] = { jv.x, jv.y, jv.z, jv.w };

    f32x4 r[4], v[4];
    #pragma unroll
    for (int k = 0; k < 4; ++k)
        r[k] = ((const f32x4*)(residual + (size_t)(bl0 + k) * DD))[d4];

    #pragma unroll
    for (int k = 0; k < 4; ++k) {
        v[k] = r[k];
        if (j[k] >= 0) {
            // share gather with previous row when j matches (register reuse)
            if (k > 0 && j[k] == j[k - 1]) {
                v[k].x = r[k].x + (v[k - 1].x - r[k - 1].x);
                v[k].y = r[k].y + (v[k - 1].y - r[k - 1].y);
                v[k].z = r[k].z + (v[k - 1].z - r[k - 1].z);
                v[k].w = r[k].w + (v[k - 1].w - r[k - 1].w);
            } else {
                const float p = ppre[(size_t)b * MM + j[k]];
                const int   c = j[k] / CC;
                const u16x4 hsu = ((const u16x4*)(hstart + ((size_t)b * NC + c) * DD))[d4];
                const u16x4 hu  = ((const u16x4*)(hloc + ((size_t)b * MM + j[k]) * DD))[d4];
                v[k].x = r[k].x + fmaf(p, bf2f(hsu.x), bf2f(hu.x));
                v[k].y = r[k].y + fmaf(p, bf2f(hsu.y), bf2f(hu.y));
                v[k].z = r[k].z + fmaf(p, bf2f(hsu.z), bf2f(hu.z));
                v[k].w = r[k].w + fmaf(p, bf2f(hsu.w), bf2f(hu.w));
            }
        }
    }
    #pragma unroll
    for (int k = 0; k < 4; ++k)
        __builtin_nontemporal_store(v[k], ((f32x4*)(out + (size_t)(bl0 + k) * DD)) + d4);
}

// ============================================================================
extern "C" void kernel_launch(void* const* d_in, const int* in_sizes, int n_in,
                              void* d_out, int out_size, void* d_ws, size_t ws_size,
                              hipStream_t stream) {
    const float* hid    = (const float*)d_in[0];   // (B,M,D) f32
    const float* res    = (const float*)d_in[1];   // (B,L,D) f32
    const void*  msk    = d_in[2];                 // (B,L) bool-ish
    const float* prob   = (const float*)d_in[3];   // (B,L) f32
    const int*   counts = (const int*)d_in[4];     // (B,) i32
    const float* state  = (const float*)d_in[5];   // (B,D) f32

    float* out       = (float*)d_out;                       // (B,L,D)
    float* out_state = out + (size_t)BB * LL * DD;          // (B,D)

    if (ws_size < WS_NEEDED) return;

    char* ws = (char*)d_ws;
    int*            cidx   = (int*)           (ws + OFF_CIDX);
    float*          decay  = (float*)         (ws + OFF_DECAY);
    float*          ppre   = (float*)         (ws + OFF_PPRE);
    float*          abuf   = (float*)         (ws + OFF_A);
    unsigned short* hstart = (unsigned short*)(ws + OFF_HSTART);
    unsigned short* hloc   = (unsigned short*)(ws + OFF_HLOC);

    hipLaunchKernelGGL(k_prep, dim3(BB), dim3(1024), 0, stream,
                       msk, prob, cidx, decay, ppre, abuf);
    hipLaunchKernelGGL(k_localscan, dim3(NC, BB), dim3(256), 0, stream,
                       hid, decay, counts, hloc);
    hipLaunchKernelGGL(k_scan, dim3(DD / 2, BB), dim3(256), 0, stream,
                       state, abuf, hloc, counts, hstart, out_state);
    hipLaunchKernelGGL(k_output, dim3(BB * LL / 4), dim3(256), 0, stream,
                       res, cidx, ppre, hstart, hloc, out);
}

// Round 19
// 77.616 us; speedup vs baseline: 1.0524x; 1.0524x over previous
//
#include <hip/hip_runtime.h>
#include <stdint.h>

// Problem dims (fixed by reference)
#define BB 8
#define LL 4096
#define DD 1024
#define MM 2048
#define CC 16            // chunk length for the two-level scan
#define NC (MM / CC)     // 128 chunks

// ---- workspace layout (bytes) ----
#define OFF_CIDX   0                                   // B*L i32    = 131072
#define OFF_DECAY  (OFF_CIDX   + (size_t)BB*LL*4)      // B*M  f32   = 65536
#define OFF_PPRE   (OFF_DECAY  + (size_t)BB*MM*4)      // B*M  f32   = 65536
#define OFF_A      (OFF_PPRE   + (size_t)BB*MM*4)      // B*NC f32   = 4096
#define OFF_HSTART (OFF_A      + (size_t)BB*NC*4)      // B*NC*D bf16 = 2 MB
#define OFF_HLOC   (OFF_HSTART + (size_t)BB*NC*DD*2)   // B*M*D bf16 = 32 MB
#define WS_NEEDED  (OFF_HLOC   + (size_t)BB*MM*DD*2)

// native clang vector types (accepted by __builtin_nontemporal_*)
typedef float          f32x4 __attribute__((ext_vector_type(4)));
typedef unsigned short u16x4 __attribute__((ext_vector_type(4)));

// ---- bf16 helpers (RNE, hand-rolled: exact bit semantics) ------------------
__device__ __forceinline__ unsigned short f2bf(float f) {
    union { float f; uint32_t u; } v; v.f = f;
    uint32_t r = v.u + 0x7FFFu + ((v.u >> 16) & 1u);
    return (unsigned short)(r >> 16);
}
__device__ __forceinline__ float bf2f(unsigned short h) {
    union { uint32_t u; float f; } v; v.u = ((uint32_t)h) << 16;
    return v.f;
}

// ============================================================================
// K1: per-batch mask cumsum, decay scatter, within-chunk prefix products.
// One block per batch; 1024 threads = 16 waves; shuffle-based scan.
// ============================================================================
__global__ __launch_bounds__(1024) void k_prep(
    const void* __restrict__ mask_raw,
    const float* __restrict__ prob,
    int* __restrict__ chunk_idx,      // (B,L)
    float* __restrict__ decay,        // (B,M)
    float* __restrict__ ppre,         // (B,M)
    float* __restrict__ abuf)         // (B,NC)
{
    const int b    = blockIdx.x;
    const int tid  = threadIdx.x;
    const int lane = tid & 63;
    const int wid  = tid >> 6;        // 0..15

    __shared__ int s_f32, s_bool;
    __shared__ int s_wsum[16];
    __shared__ int s_woff[17];
    __shared__ float s_decay[MM];

    // ---- detect mask storage: scan first 32768 bytes (safe in all layouts) --
    const uint32_t* w = (const uint32_t*)mask_raw;
    int lf32 = 0, lbool = 0;
    for (int i = tid; i < 8192; i += 1024) {
        uint32_t v = w[i];
        if (v == 0x3F800000u) lf32 = 1;          // a 1.0f word -> f32 storage
        if (v & 0xFFFFFF00u)  lbool = 1;         // nonzero high bytes -> 1-byte
    }
    if (tid == 0) { s_f32 = 0; s_bool = 0; s_woff[0] = 0; }
    for (int j = tid; j < MM; j += 1024) s_decay[j] = 1.0f;
    __syncthreads();
    if (lf32)  s_f32 = 1;
    if (lbool) s_bool = 1;
    __syncthreads();
    const int mode = s_f32 ? 2 : (s_bool ? 1 : 0);   // 2=f32, 1=byte, 0=int32

    auto rdmask = [&](int l) -> int {
        size_t idx = (size_t)b * LL + l;
        if (mode == 2) return ((const float*)mask_raw)[idx] != 0.0f;
        if (mode == 1) return ((const unsigned char*)mask_raw)[idx] != 0;
        return ((const int*)mask_raw)[idx] != 0;
    };

    const int l0 = tid * 4;
    const int m0 = rdmask(l0 + 0);
    const int m1 = rdmask(l0 + 1);
    const int m2 = rdmask(l0 + 2);
    const int m3 = rdmask(l0 + 3);
    const int s  = m0 + m1 + m2 + m3;

    // wave-level inclusive scan of per-thread sums (no barriers)
    int incl = s;
    #pragma unroll
    for (int off = 1; off < 64; off <<= 1) {
        int v = __shfl_up(incl, off);
        if (lane >= off) incl += v;
    }
    if (lane == 63) s_wsum[wid] = incl;
    __syncthreads();

    // wave 0 scans the 16 wave totals
    if (wid == 0) {
        int v = (lane < 16) ? s_wsum[lane] : 0;
        #pragma unroll
        for (int off = 1; off < 16; off <<= 1) {
            int u = __shfl_up(v, off);
            if (lane >= off) v += u;
        }
        if (lane < 16) s_woff[lane + 1] = v;
    }
    __syncthreads();

    const int excl = s_woff[wid] + incl - s;   // tokens before this thread's 4

    const int c0 = excl + m0;
    const int c1 = c0 + m1;
    const int c2 = c1 + m2;
    const int c3 = c2 + m3;

    chunk_idx[(size_t)b * LL + l0 + 0] = c0 - 1;
    chunk_idx[(size_t)b * LL + l0 + 1] = c1 - 1;
    chunk_idx[(size_t)b * LL + l0 + 2] = c2 - 1;
    chunk_idx[(size_t)b * LL + l0 + 3] = c3 - 1;

    // scatter decay = clamp(1-prob,0,1) at masked slots (into LDS)
    if (m0) { float v = 1.0f - prob[(size_t)b*LL + l0+0]; s_decay[c0-1] = fminf(fmaxf(v,0.f),1.f); }
    if (m1) { float v = 1.0f - prob[(size_t)b*LL + l0+1]; s_decay[c1-1] = fminf(fmaxf(v,0.f),1.f); }
    if (m2) { float v = 1.0f - prob[(size_t)b*LL + l0+2]; s_decay[c2-1] = fminf(fmaxf(v,0.f),1.f); }
    if (m3) { float v = 1.0f - prob[(size_t)b*LL + l0+3]; s_decay[c3-1] = fminf(fmaxf(v,0.f),1.f); }
    __syncthreads();

    for (int j = tid; j < MM; j += 1024) decay[(size_t)b * MM + j] = s_decay[j];
    if (tid < NC) {
        float p = 1.0f;
        const int t0 = tid * CC;
        #pragma unroll
        for (int t = 0; t < CC; ++t) {
            p *= s_decay[t0 + t];
            ppre[(size_t)b * MM + t0 + t] = p;
        }
        abuf[b * NC + tid] = p;
    }
}

// ============================================================================
// K2: per-chunk local EMA scans (zero init), bf16 output. Plain cached loads
// (NT loads measured −8%: round 16). grid = (NC, B), 256 threads.
// ============================================================================
__global__ __launch_bounds__(256) void k_localscan(
    const float* __restrict__ hid,     // (B,M,D) f32
    const float* __restrict__ decay,   // (B,M)
    const int* __restrict__ counts,
    unsigned short* __restrict__ hloc) // (B,M,D) bf16
{
    const int c = blockIdx.x;
    const int b = blockIdx.y;
    const int count = counts[b];
    const int tstart = c * CC;
    const int tend = min(CC, count - tstart);
    if (tend <= 0) return;

    __shared__ float s_a[CC];
    if (threadIdx.x < CC) s_a[threadIdx.x] = decay[(size_t)b * MM + tstart + threadIdx.x];
    __syncthreads();

    const int d4 = threadIdx.x;
    const float4*  x = (const float4*)(hid + ((size_t)b * MM + tstart) * DD) + d4;
    ushort4*       o = (ushort4*)(hloc + ((size_t)b * MM + tstart) * DD) + d4;

    float4 h = make_float4(0.f, 0.f, 0.f, 0.f);
    #pragma unroll 4
    for (int t = 0; t < tend; ++t) {
        const float a  = s_a[t];
        const float om = 1.0f - a;
        const float4 xv = x[(size_t)t * (DD / 4)];
        h.x = fmaf(a, h.x, om * xv.x);
        h.y = fmaf(a, h.y, om * xv.y);
        h.z = fmaf(a, h.z, om * xv.z);
        h.w = fmaf(a, h.w, om * xv.w);
        ushort4 u;
        u.x = f2bf(h.x); u.y = f2bf(h.y); u.z = f2bf(h.z); u.w = f2bf(h.w);
        o[(size_t)t * (DD / 4)] = u;
    }
}

// ============================================================================
// K3: parallel (Kogge-Stone) scan over the 128 chunks -> chunk-start states
// (bf16) and new_state (f32). grid = (D/2, B).
// ============================================================================
__global__ __launch_bounds__(256) void k_scan(
    const float* __restrict__ state,            // (B,D)
    const float* __restrict__ abuf,             // (B,NC)
    const unsigned short* __restrict__ hloc,    // (B,M,D) bf16
    const int* __restrict__ counts,
    unsigned short* __restrict__ hstart,        // (B,NC,D) bf16
    float* __restrict__ out_state)              // (B,D) f32
{
    const int g  = blockIdx.x;             // channel group of 2
    const int b  = blockIdx.y;
    const int tid = threadIdx.x;
    const int c  = tid >> 1;               // 0..127
    const int i  = tid & 1;
    const int ch = g * 2 + i;
    const int count = counts[b];
    const int tstart = c * CC;

    float a = abuf[b * NC + c];
    float e = 0.0f;
    if (tstart < count) {
        const int row = min(tstart + CC - 1, count - 1);
        e = bf2f(hloc[((size_t)b * MM + row) * DD + ch]);
    }

    __shared__ float s_a[NC];
    __shared__ float s_e[NC][2];

    for (int off = 1; off < NC; off <<= 1) {
        s_a[c] = a;              // 2 threads write the same value: benign
        s_e[c][i] = e;
        __syncthreads();
        if (c >= off) {
            const float ap = s_a[c - off];
            const float ep = s_e[c - off][i];
            e = fmaf(a, ep, e);
            a = a * ap;
        }
        __syncthreads();
    }
    s_a[c] = a;
    s_e[c][i] = e;
    __syncthreads();

    const float st = state[(size_t)b * DD + ch];
    const float hs = (c == 0) ? st : fmaf(s_a[c - 1], st, s_e[c - 1][i]);
    hstart[((size_t)b * NC + c) * DD + ch] = f2bf(hs);
    if (c == NC - 1) out_state[(size_t)b * DD + ch] = fmaf(a, st, e);
}

// ============================================================================
// K4: output = residual + gathered EMA; 2 rows per block; NT stores on out;
// XCD-chunked swizzle: swz=(bid&7)*2048+(bid>>3) is bijective on 16384 blocks
// and gives each XCD one contiguous batch -> hstart (256KB/batch) + hloc
// (4MB/batch) L2-resident. grid = B*L/2 = 16384, 256 threads.
// ============================================================================
__global__ __launch_bounds__(256) void k_output(
    const float* __restrict__ residual,         // (B,L,D)
    const int* __restrict__ chunk_idx,          // (B,L)
    const float* __restrict__ ppre,             // (B,M)
    const unsigned short* __restrict__ hstart,  // (B,NC,D) bf16
    const unsigned short* __restrict__ hloc,    // (B,M,D) bf16
    float* __restrict__ out)                    // (B,L,D)
{
    // XCD-chunked bijective swizzle (16384 = 8 * 2048)
    const int swz = ((blockIdx.x & 7) << 11) | (blockIdx.x >> 3);
    const int bl0 = swz * 2;            // first of 2 rows (same batch: L even)
    const int b   = bl0 >> 12;          // L = 4096
    const int d4  = threadIdx.x;

    const int j0 = chunk_idx[bl0];
    const int j1 = chunk_idx[bl0 + 1];

    const f32x4 r0 = ((const f32x4*)(residual + (size_t)bl0 * DD))[d4];
    const f32x4 r1 = ((const f32x4*)(residual + ((size_t)bl0 + 1) * DD))[d4];

    f32x4 v0 = r0, v1 = r1;
    if (j0 >= 0) {
        const float p = ppre[(size_t)b * MM + j0];
        const int   c = j0 / CC;
        const u16x4 hsu = ((const u16x4*)(hstart + ((size_t)b * NC + c) * DD))[d4];
        const u16x4 hu  = ((const u16x4*)(hloc + ((size_t)b * MM + j0) * DD))[d4];
        v0.x = r0.x + fmaf(p, bf2f(hsu.x), bf2f(hu.x));
        v0.y = r0.y + fmaf(p, bf2f(hsu.y), bf2f(hu.y));
        v0.z = r0.z + fmaf(p, bf2f(hsu.z), bf2f(hu.z));
        v0.w = r0.w + fmaf(p, bf2f(hsu.w), bf2f(hu.w));
    }
    if (j1 >= 0) {
        const float p = ppre[(size_t)b * MM + j1];
        const int   c = j1 / CC;
        const u16x4 hsu = ((const u16x4*)(hstart + ((size_t)b * NC + c) * DD))[d4];
        const u16x4 hu  = ((const u16x4*)(hloc + ((size_t)b * MM + j1) * DD))[d4];
        v1.x = r1.x + fmaf(p, bf2f(hsu.x), bf2f(hu.x));
        v1.y = r1.y + fmaf(p, bf2f(hsu.y), bf2f(hu.y));
        v1.z = r1.z + fmaf(p, bf2f(hsu.z), bf2f(hu.z));
        v1.w = r1.w + fmaf(p, bf2f(hsu.w), bf2f(hu.w));
    }
    __builtin_nontemporal_store(v0, ((f32x4*)(out + (size_t)bl0 * DD)) + d4);
    __builtin_nontemporal_store(v1, ((f32x4*)(out + ((size_t)bl0 + 1) * DD)) + d4);
}

// ============================================================================
extern "C" void kernel_launch(void* const* d_in, const int* in_sizes, int n_in,
                              void* d_out, int out_size, void* d_ws, size_t ws_size,
                              hipStream_t stream) {
    const float* hid    = (const float*)d_in[0];   // (B,M,D) f32
    const float* res    = (const float*)d_in[1];   // (B,L,D) f32
    const void*  msk    = d_in[2];                 // (B,L) bool-ish
    const float* prob   = (const float*)d_in[3];   // (B,L) f32
    const int*   counts = (const int*)d_in[4];     // (B,) i32
    const float* state  = (const float*)d_in[5];   // (B,D) f32

    float* out       = (float*)d_out;                       // (B,L,D)
    float* out_state = out + (size_t)BB * LL * DD;          // (B,D)

    if (ws_size < WS_NEEDED) return;

    char* ws = (char*)d_ws;
    int*            cidx   = (int*)           (ws + OFF_CIDX);
    float*          decay  = (float*)         (ws + OFF_DECAY);
    float*          ppre   = (float*)         (ws + OFF_PPRE);
    float*          abuf   = (float*)         (ws + OFF_A);
    unsigned short* hstart = (unsigned short*)(ws + OFF_HSTART);
    unsigned short* hloc   = (unsigned short*)(ws + OFF_HLOC);

    hipLaunchKernelGGL(k_prep, dim3(BB), dim3(1024), 0, stream,
                       msk, prob, cidx, decay, ppre, abuf);
    hipLaunchKernelGGL(k_localscan, dim3(NC, BB), dim3(256), 0, stream,
                       hid, decay, counts, hloc);
    hipLaunchKernelGGL(k_scan, dim3(DD / 2, BB), dim3(256), 0, stream,
                       state, abuf, hloc, counts, hstart, out_state);
    hipLaunchKernelGGL(k_output, dim3(BB * LL / 2), dim3(256), 0, stream,
                       res, cidx, ppre, hstart, hloc, out);
}